// Round 2
// baseline (284.827 us; speedup 1.0000x reference)
//
#include <hip/hip_runtime.h>
#include <stdint.h>

#define D_MODEL 1024
#define D_FF    4096
#define NROWS   8192   // 4 * 2048

typedef __attribute__((ext_vector_type(4))) float f32x4;
typedef __attribute__((ext_vector_type(8))) short short8;

__device__ __forceinline__ unsigned short f2bf(float f) {
  unsigned u = __float_as_uint(f);
  u += 0x7fffu + ((u >> 16) & 1u);   // round-to-nearest-even
  return (unsigned short)(u >> 16);
}

// ---------------- LayerNorm (fp32 in) -> bf16 out ----------------
__global__ __launch_bounds__(256) void ln_bf16_kernel(
    const float* __restrict__ x, const float* __restrict__ lnw,
    const float* __restrict__ lnb, unsigned short* __restrict__ y) {
  const int row = blockIdx.x;
  const int t = threadIdx.x;
  const int w = t >> 6, l = t & 63;
  const float4* xr = (const float4*)(x + (size_t)row * D_MODEL);
  float4 v = xr[t];
  float s  = v.x + v.y + v.z + v.w;
  float s2 = v.x * v.x + v.y * v.y + v.z * v.z + v.w * v.w;
#pragma unroll
  for (int o = 32; o >= 1; o >>= 1) {
    s  += __shfl_xor(s, o);
    s2 += __shfl_xor(s2, o);
  }
  __shared__ float red[8];
  if (l == 0) { red[w] = s; red[4 + w] = s2; }
  __syncthreads();
  s  = red[0] + red[1] + red[2] + red[3];
  s2 = red[4] + red[5] + red[6] + red[7];
  const float mu  = s * (1.0f / D_MODEL);
  const float var = s2 * (1.0f / D_MODEL) - mu * mu;
  const float rs  = rsqrtf(var + 1e-5f);
  float4 wv = ((const float4*)lnw)[t];
  float4 bv = ((const float4*)lnb)[t];
  ushort4 o4;
  o4.x = f2bf((v.x - mu) * rs * wv.x + bv.x);
  o4.y = f2bf((v.y - mu) * rs * wv.y + bv.y);
  o4.z = f2bf((v.z - mu) * rs * wv.z + bv.z);
  o4.w = f2bf((v.w - mu) * rs * wv.w + bv.w);
  *(ushort4*)(y + (size_t)row * D_MODEL + t * 4) = o4;
}

// ------------- transpose + fp32->bf16 convert: dst[C][R] = src[R][C] -------------
__global__ __launch_bounds__(256) void transpose_f32_bf16(
    const float* __restrict__ src, unsigned short* __restrict__ dst,
    int R, int C) {
  __shared__ float tile[32][33];
  const int tx = threadIdx.x;  // 0..31
  const int ty = threadIdx.y;  // 0..7
  const int r0 = blockIdx.y * 32, c0 = blockIdx.x * 32;
#pragma unroll
  for (int i = 0; i < 32; i += 8)
    tile[ty + i][tx] = src[(size_t)(r0 + ty + i) * C + (c0 + tx)];
  __syncthreads();
#pragma unroll
  for (int i = 0; i < 32; i += 8)
    dst[(size_t)(c0 + ty + i) * R + (r0 + tx)] = f2bf(tile[tx][ty + i]);
}

// ---------------- bf16 GEMM, C = A @ Bt^T (+bias, opt ReLU) ----------------
// A:  [M][K] bf16 bits, row-major
// Bt: [N][K] bf16 bits, row-major (i.e. B transposed)
// m97 structure: 128x128 tile, BK=64, 4 waves (2x2), each wave 64x64 = 4x4
// fragments of 16x16, global_load_lds width 16 into linear LDS.
template <int RELU, int BF16OUT>
__global__ __launch_bounds__(256, 3) void gemm_bt(
    const unsigned short* __restrict__ A, const unsigned short* __restrict__ Bt,
    const float* __restrict__ bias, unsigned short* __restrict__ Cb,
    float* __restrict__ Cf, int M, int N, int K) {
  constexpr int BM = 128, BN = 128, BK = 64;
  __shared__ short lA[BM * BK];
  __shared__ short lB[BN * BK];
  const int t = threadIdx.x;
  const int w = t >> 6, l = t & 63;
  const int bm0 = blockIdx.y * BM, bn0 = blockIdx.x * BN;
  const int wm = (w >> 1) * 64, wn = (w & 1) * 64;

  f32x4 acc[4][4];
  const f32x4 zero = {0.f, 0.f, 0.f, 0.f};
#pragma unroll
  for (int i = 0; i < 4; ++i)
#pragma unroll
    for (int j = 0; j < 4; ++j) acc[i][j] = zero;

  const int nkt = K / BK;
  for (int kt = 0; kt < nkt; ++kt) {
    const int k0 = kt * BK;
    // Stage A and B tiles: 16 chunks each of (64 lanes x 16B); wave w takes
    // chunks {w, w+4, w+8, w+12}. LDS dest = uniform base + lane*16 (required).
#pragma unroll
    for (int p = 0; p < 4; ++p) {
      const int eb = (((p * 4 + w) * 64) + l) * 8;  // element offset in tile
      const int r = eb >> 6, c = eb & 63;
      __builtin_amdgcn_global_load_lds(
          (const __attribute__((address_space(1))) void*)(A + (size_t)(bm0 + r) * K + (k0 + c)),
          (__attribute__((address_space(3))) void*)(&lA[eb]), 16, 0, 0);
      __builtin_amdgcn_global_load_lds(
          (const __attribute__((address_space(1))) void*)(Bt + (size_t)(bn0 + r) * K + (k0 + c)),
          (__attribute__((address_space(3))) void*)(&lB[eb]), 16, 0, 0);
    }
    __syncthreads();  // compiler emits vmcnt(0) drain before s_barrier

    const short8* pA = (const short8*)lA;
    const short8* pB = (const short8*)lB;
#pragma unroll
    for (int kb = 0; kb < 2; ++kb) {
      short8 af[4], bfr[4];
      const int kc = kb * 4 + (l >> 4);  // granule column (8 bf16 per granule)
#pragma unroll
      for (int f = 0; f < 4; ++f) {
        af[f]  = pA[(wm + f * 16 + (l & 15)) * 8 + kc];
        bfr[f] = pB[(wn + f * 16 + (l & 15)) * 8 + kc];
      }
#pragma unroll
      for (int fm = 0; fm < 4; ++fm)
#pragma unroll
        for (int fn = 0; fn < 4; ++fn)
          acc[fm][fn] = __builtin_amdgcn_mfma_f32_16x16x32_bf16(
              af[fm], bfr[fn], acc[fm][fn], 0, 0, 0);
    }
    __syncthreads();
  }

  // Epilogue: D(m,n) per verified layout:
  // col = lane&15, row = (lane>>4)*4 + reg
#pragma unroll
  for (int fn = 0; fn < 4; ++fn) {
    const int n = bn0 + wn + fn * 16 + (l & 15);
    const float bv = bias[n];
#pragma unroll
    for (int fm = 0; fm < 4; ++fm) {
      const int mbase = bm0 + wm + fm * 16 + ((l >> 4) * 4);
#pragma unroll
      for (int j = 0; j < 4; ++j) {
        float v = acc[fm][fn][j] + bv;
        if (RELU) v = v > 0.f ? v : 0.f;
        if (BF16OUT) Cb[(size_t)(mbase + j) * N + n] = f2bf(v);
        else         Cf[(size_t)(mbase + j) * N + n] = v;
      }
    }
  }
}

extern "C" void kernel_launch(void* const* d_in, const int* in_sizes, int n_in,
                              void* d_out, int out_size, void* d_ws, size_t ws_size,
                              hipStream_t stream) {
  const float* x   = (const float*)d_in[0];
  const float* lnw = (const float*)d_in[1];
  const float* lnb = (const float*)d_in[2];
  const float* w1  = (const float*)d_in[3];
  const float* b1  = (const float*)d_in[4];
  const float* w2  = (const float*)d_in[5];
  const float* b2  = (const float*)d_in[6];
  float* out = (float*)d_out;

  char* ws = (char*)d_ws;
  unsigned short* x_ln = (unsigned short*)(ws);                      // 16 MB
  unsigned short* w1t  = (unsigned short*)(ws + (16u << 20));        //  8 MB
  unsigned short* w2t  = (unsigned short*)(ws + (24u << 20));        //  8 MB
  unsigned short* h    = (unsigned short*)(ws + (32u << 20));        // 64 MB
  // total workspace use: 96 MB

  ln_bf16_kernel<<<NROWS, 256, 0, stream>>>(x, lnw, lnb, x_ln);
  transpose_f32_bf16<<<dim3(D_FF / 32, D_MODEL / 32), dim3(32, 8), 0, stream>>>(
      w1, w1t, D_MODEL, D_FF);
  transpose_f32_bf16<<<dim3(D_MODEL / 32, D_FF / 32), dim3(32, 8), 0, stream>>>(
      w2, w2t, D_FF, D_MODEL);
  // h = ReLU(x_ln @ w1 + b1), bf16
  gemm_bt<1, 1><<<dim3(D_FF / 128, NROWS / 128), 256, 0, stream>>>(
      x_ln, w1t, b1, h, nullptr, NROWS, D_FF, D_MODEL);
  // out = h @ w2 + b2, fp32
  gemm_bt<0, 0><<<dim3(D_MODEL / 128, NROWS / 128), 256, 0, stream>>>(
      h, w2t, b2, nullptr, out, NROWS, D_MODEL, D_FF);
}